// Round 12
// baseline (138.191 us; speedup 1.0000x reference)
//
#include <hip/hip_runtime.h>
#include <hip/hip_bf16.h>

#define VDIM 50257
#define EDIM 128
#define MROWS 2048
#define KMAIN 50240            // 1570 k-steps of 32; tail of 17 in fp32 in k_reduce
#define KTAIL 17               // VDIM - KMAIN
#define KSTEPS 1570
#define SPLIT 16
#define BM 32
#define BKS 4                  // k-steps per superstep (BK = 128)
#define NSS 25                 // ceil(nsteps/BKS), nsteps = 98 or 99
#define PITCH2 272             // bytes per LDS row (136 shorts): rows offset 4 banks
#define LB (BM * PITCH2)       // 8704 B per buffer

using short8_t = __attribute__((ext_vector_type(8))) short;
using float4_t = __attribute__((ext_vector_type(4))) float;

static __device__ __forceinline__ short f2bf(float f) {
    union { __hip_bfloat16 h; short s; } u;
    u.h = __float2bfloat16(f);
    return u.s;
}

// W (VDIM x EDIM fp32) -> Wt2[step][128 e][32 k] bf16 (each 8 KB B-tile contiguous).
__global__ __launch_bounds__(256) void k_wt2(const float* __restrict__ W,
                                             short* __restrict__ Wt2) {
    __shared__ float tile[32][132];             // +4 pad for column reads
    const int t = threadIdx.x;
    const int step = blockIdx.x;                // 0..1569
    const float* src = W + (size_t)step * 4096; // 32 k-rows x 128 e, contiguous
    #pragma unroll
    for (int p = 0; p < 16; ++p) {
        int idx = p * 256 + t;
        tile[idx >> 7][idx & 127] = src[idx];
    }
    __syncthreads();
    const int e = t >> 1, half = t & 1;
    short* dst = Wt2 + (size_t)step * 4096 + e * 32 + half * 16;
    #pragma unroll
    for (int q = 0; q < 2; ++q) {
        short8_t pk;
        #pragma unroll
        for (int i = 0; i < 8; ++i) pk[i] = f2bf(tile[half * 16 + q * 8 + i][e]);
        *reinterpret_cast<short8_t*>(dst + q * 8) = pk;
    }
}

// Split-K bf16 MFMA GEMM — never-drain pipeline, block-shared staging.
// Fixes vs R6: raw s_barrier (no vmcnt drain), depth-2 reg prefetch (write
// doesn't drain), B-first issue order (counted waits skip A), aligned dword
// A-loads (no 16B-misalign splits). One barrier per 128-k superstep.
// Grid 1024 = 64 mt x 16 s, 4 blocks/CU; s=bid&15 XCD-pins splits (L2 Wt2).
__global__ __launch_bounds__(256, 4) void k_main(const float* __restrict__ A,
                                                 const short* __restrict__ Wt2,
                                                 float* __restrict__ P) {
    __shared__ short lds[2 * BM * (PITCH2 / 2)];   // 17408 B, double-buffered

    const int bid = blockIdx.x;
    const int s   = bid & 15;
    const int mt  = bid >> 4;
    const int t = threadIdx.x, w = t >> 6, l = t & 63;

    const int start  = (s * KSTEPS) / SPLIT;
    const int end    = ((s + 1) * KSTEPS) / SPLIT;
    const int nsteps = end - start;             // 98 or 99
    const size_t kb  = (size_t)start * 32;

    // staging: thread covers row 8w+(l>>3), dwords (l&7)+8q, q=0..15.
    // Per instr: 8 rows x 32 B aligned pieces; per-thread stride 32 B (no fuse).
    const int srow = 8 * w + (l >> 3);
    const int sdw  = l & 7;
    const float* aRow = A + (size_t)(mt * BM + srow) * VDIM + kb + sdw;

    // fragment identity: wave w owns col-fragments {2w, 2w+1}
    const int rl = l & 15, kg = l >> 4;
    const int cf0 = 2 * w;

    char* const lb = (char*)&lds[0];
    const int fr0 = rl * PITCH2 + kg * 16;      // rowfrag 0 read offset
    const int fr1 = fr0 + 16 * PITCH2;          // rowfrag 1
    const int swb = srow * PITCH2 + sdw * 2;    // write base (+16q per q)

    float4_t acc[2][2];
    #pragma unroll
    for (int i = 0; i < 2; ++i)
        #pragma unroll
        for (int j = 0; j < 2; ++j) acc[i][j] = (float4_t){0.f, 0.f, 0.f, 0.f};

    float fsA[16], fsB[16];                     // depth-2 prefetch, 32 VGPR
    short8_t breg[BKS][2];                      // 32 VGPR

    auto nk_of = [&](int ssn) {
        int r = nsteps - ssn * BKS;
        return r < 0 ? 0 : (r > BKS ? BKS : r);
    };
    auto loadA = [&](float (&fs)[16], int ssn, int nk) {
        const float* p = aRow + (size_t)ssn * 128;
        #pragma unroll
        for (int q = 0; q < 16; ++q)
            if (q < nk * 4) fs[q] = p[8 * q];   // aligned dword, wave-uniform guard
    };
    auto writeA = [&](float (&fs)[16], int buf, int nk) {
        char* base = lb + buf * LB + swb;
        #pragma unroll
        for (int q = 0; q < 16; ++q)
            if (q < nk * 4) *reinterpret_cast<short*>(base + 16 * q) = f2bf(fs[q]);
    };
    auto bpre = [&](int g0, int curn) {
        #pragma unroll
        for (int j = 0; j < BKS; ++j)
            if (j < curn) {
                const short* bb = Wt2 + (size_t)(g0 + j) * 4096
                                + (size_t)(cf0 * 16 + rl) * 32 + kg * 8;
                breg[j][0] = *reinterpret_cast<const short8_t*>(bb);
                breg[j][1] = *reinterpret_cast<const short8_t*>(bb + 512);
            }
    };
    auto computeSS = [&](int buf, int curn) {
        #pragma unroll
        for (int j = 0; j < BKS; ++j)
            if (j < curn) {
                short8_t a0 = *reinterpret_cast<const short8_t*>(lb + buf * LB + fr0 + j * 64);
                short8_t a1 = *reinterpret_cast<const short8_t*>(lb + buf * LB + fr1 + j * 64);
                acc[0][0] = __builtin_amdgcn_mfma_f32_16x16x32_bf16(a0, breg[j][0], acc[0][0], 0, 0, 0);
                acc[0][1] = __builtin_amdgcn_mfma_f32_16x16x32_bf16(a0, breg[j][1], acc[0][1], 0, 0, 0);
                acc[1][0] = __builtin_amdgcn_mfma_f32_16x16x32_bf16(a1, breg[j][0], acc[1][0], 0, 0, 0);
                acc[1][1] = __builtin_amdgcn_mfma_f32_16x16x32_bf16(a1, breg[j][1], acc[1][1], 0, 0, 0);
            }
    };

    auto iter = [&](int ss, float (&fill)[16], float (&wr)[16]) {
        const int curn = nk_of(ss);
        const int g0   = start + ss * BKS;
        bpre(g0, curn);                         // B-frags: OLDEST in vm order
        __builtin_amdgcn_sched_barrier(0);
        const int n2 = nk_of(ss + 2);
        if (n2 > 0) loadA(fill, ss + 2, n2);    // A-batch ss+2: YOUNGEST
        __builtin_amdgcn_sched_barrier(0);
        computeSS(ss & 1, curn);                // B-wait (counted) leaves fill in flight
        const int n1 = nk_of(ss + 1);
        if (n1 > 0) writeA(wr, (ss + 1) & 1, n1);  // wr loads are old: no drain of fill
        asm volatile("s_waitcnt lgkmcnt(0)" ::: "memory");  // ds_writes visible
        __builtin_amdgcn_sched_barrier(0);
        __builtin_amdgcn_s_barrier();           // raw barrier: vm queue survives
    };

    // prologue: batches 0,1 in flight; write 0 (counted wait keeps batch 1 live)
    loadA(fsA, 0, nk_of(0));
    loadA(fsB, 1, nk_of(1));
    writeA(fsA, 0, nk_of(0));
    asm volatile("s_waitcnt lgkmcnt(0)" ::: "memory");
    __builtin_amdgcn_sched_barrier(0);
    __builtin_amdgcn_s_barrier();

    #pragma unroll 1
    for (int sp = 0; sp < NSS; sp += 2) {
        iter(sp, fsA, fsB);                     // fill fsA<-sp+2, write fsB(sp+1)
        if (sp + 1 < NSS) iter(sp + 1, fsB, fsA);
    }

    // Partial write: C/D layout col = lane&15, row = (lane>>4)*4 + j  [m89-verified]
    float* pout = P + ((size_t)s * MROWS + (size_t)mt * BM) * EDIM + cf0 * 16;
    #pragma unroll
    for (int rf = 0; rf < 2; ++rf)
        #pragma unroll
        for (int cf = 0; cf < 2; ++cf)
            #pragma unroll
            for (int j = 0; j < 4; ++j) {
                int rr = rf * 16 + kg * 4 + j;
                int cc = cf * 16 + rl;
                pout[(size_t)rr * EDIM + cc] = acc[rf][cf][j];
            }
}

// out = bias + sum of SPLIT partials + fp32 K-tail, float4-vectorized.
__global__ __launch_bounds__(256) void k_reduce(const float* __restrict__ P,
                                                const float* __restrict__ A,
                                                const float* __restrict__ W,
                                                const float* __restrict__ bias,
                                                float* __restrict__ out) {
    const int i4 = blockIdx.x * 256 + threadIdx.x;   // float4 index, 65536 total
    const int m  = i4 >> 5;                          // 32 float4 per output row
    const int e4 = i4 & 31;
    float4_t acc = reinterpret_cast<const float4_t*>(bias)[e4];
    #pragma unroll
    for (int j = 0; j < KTAIL; ++j) {
        float a = A[(size_t)m * VDIM + KMAIN + j];
        float4_t w = reinterpret_cast<const float4_t*>(W + (size_t)(KMAIN + j) * EDIM)[e4];
        acc += a * w;
    }
    float4_t ps = {0.f, 0.f, 0.f, 0.f};
    #pragma unroll
    for (int p = 0; p < SPLIT; ++p)
        ps += reinterpret_cast<const float4_t*>(P)[(size_t)p * (MROWS * EDIM / 4) + i4];
    acc += ps;
    reinterpret_cast<float4_t*>(out)[i4] = acc;
}

// Emergency fallback if workspace is too small: plain fp32, deterministic.
__global__ __launch_bounds__(256) void k_naive(const float* __restrict__ A,
                                               const float* __restrict__ W,
                                               const float* __restrict__ bias,
                                               float* __restrict__ out) {
    const int e  = threadIdx.x & 127;
    const int mi = threadIdx.x >> 7;
    const int m0 = blockIdx.x * 8 + mi;
    float acc[4] = {0.f, 0.f, 0.f, 0.f};
    for (int k = 0; k < VDIM; ++k) {
        float w = W[(size_t)k * EDIM + e];
        #pragma unroll
        for (int q = 0; q < 4; ++q)
            acc[q] += A[(size_t)(m0 + q * 2) * VDIM + k] * w;
    }
    #pragma unroll
    for (int q = 0; q < 4; ++q)
        out[(size_t)(m0 + q * 2) * EDIM + e] = acc[q] + bias[e];
}

extern "C" void kernel_launch(void* const* d_in, const int* in_sizes, int n_in,
                              void* d_out, int out_size, void* d_ws, size_t ws_size,
                              hipStream_t stream) {
    const float* A    = (const float*)d_in[0];  // (16,128,50257) fp32
    const float* W    = (const float*)d_in[1];  // (50257,128) fp32
    const float* bias = (const float*)d_in[2];  // (128,) fp32
    float* out = (float*)d_out;                 // (16,128,128) fp32

    const size_t WT2_BYTES = (size_t)KSTEPS * 4096 * sizeof(short);         // 12.86 MB
    const size_t P_BYTES   = (size_t)SPLIT * MROWS * EDIM * sizeof(float);  // 16.78 MB

    if (ws_size >= WT2_BYTES + P_BYTES) {
        short* Wt2 = (short*)d_ws;
        float* P   = (float*)((char*)d_ws + WT2_BYTES);
        k_wt2<<<KSTEPS, 256, 0, stream>>>(W, Wt2);
        k_main<<<(MROWS / BM) * SPLIT, 256, 0, stream>>>(A, Wt2, P);
        k_reduce<<<(MROWS * EDIM) / (256 * 4), 256, 0, stream>>>(P, A, W, bias, out);
    } else {
        k_naive<<<MROWS / 8, 256, 0, stream>>>(A, W, bias, out);
    }
}

// Round 13
// 129.513 us; speedup vs baseline: 1.0670x; 1.0670x over previous
//
#include <hip/hip_runtime.h>
#include <hip/hip_bf16.h>

#define VDIM 50257
#define EDIM 128
#define MROWS 2048
#define KMAIN 50240            // 1570 k-steps of 32; tail of 17 in fp32 in k_reduce
#define KTAIL 17               // VDIM - KMAIN
#define KSTEPS 1570
#define SPLIT 24
#define BM 32
#define BKS 8                  // k-steps per superstep (BK = 256)
#define PITCH 264              // shorts per LDS row (528 B): b128 reads hit 8-cy minimum
#define LB (BM * PITCH * 2)    // 16896 B, SINGLE buffer -> 6 blocks/CU

using short8_t = __attribute__((ext_vector_type(8))) short;
using float4_t = __attribute__((ext_vector_type(4))) float;

static __device__ __forceinline__ short f2bf(float f) {
    union { __hip_bfloat16 h; short s; } u;
    u.h = __float2bfloat16(f);
    return u.s;
}

static __device__ __forceinline__ unsigned pack_bf2(float lo, float hi) {
    unsigned l = (unsigned short)f2bf(lo);
    unsigned h = (unsigned short)f2bf(hi);
    return l | (h << 16);
}

// W (VDIM x EDIM fp32) -> Wt2[step][128 e][32 k] bf16 (each 8 KB B-tile contiguous).
__global__ __launch_bounds__(256) void k_wt2(const float* __restrict__ W,
                                             short* __restrict__ Wt2) {
    __shared__ float tile[32][132];             // +4 pad for column reads
    const int t = threadIdx.x;
    const int step = blockIdx.x;                // 0..1569
    const float* src = W + (size_t)step * 4096; // 32 k-rows x 128 e, contiguous
    #pragma unroll
    for (int p = 0; p < 16; ++p) {
        int idx = p * 256 + t;
        tile[idx >> 7][idx & 127] = src[idx];
    }
    __syncthreads();
    const int e = t >> 1, half = t & 1;
    short* dst = Wt2 + (size_t)step * 4096 + e * 32 + half * 16;
    #pragma unroll
    for (int q = 0; q < 2; ++q) {
        short8_t pk;
        #pragma unroll
        for (int i = 0; i < 8; ++i) pk[i] = f2bf(tile[half * 16 + q * 8 + i][e]);
        *reinterpret_cast<short8_t*>(dst + q * 8) = pk;
    }
}

// Split-K bf16 MFMA GEMM — the untested grid cell: HIGH OCCUPANCY (6 blocks/CU,
// 24 waves) x 1KB-PER-INSTRUCTION A-loads (R6's two proven levers combined).
// Single-buffer BK=256 LDS (16.9 KB), two raw s_barriers per superstep (no
// vmcnt drain), depth-1 reg prefetch issued before compute.
// Grid 1536 = 64 mt x 24 s (exactly 6/CU); s%8 = XCD -> 2.4 MB Wt2/XCD in L2.
__global__ __launch_bounds__(256, 6) void k_main(const float* __restrict__ A,
                                                 const short* __restrict__ Wt2,
                                                 float* __restrict__ P) {
    __shared__ short lds[BM * PITCH];           // 16896 B, single buffer

    const int bid = blockIdx.x;
    const int s   = bid % SPLIT;                // s%8 == bid%8 -> XCD-pinned
    const int mt  = bid / SPLIT;                // 0..63
    const int t = threadIdx.x, w = t >> 6, l = t & 63;

    const int start  = (s * KSTEPS) / SPLIT;
    const int end    = ((s + 1) * KSTEPS) / SPLIT;
    const int nsteps = end - start;             // 65 or 66
    const int NSS    = (nsteps + BKS - 1) / BKS;
    const size_t kb  = (size_t)start * 32;

    // stage identity: wave w owns rows 8w..8w+7; instr i = row 8w+i, lane l
    // covers floats 4l..4l+3 -> 64 lanes x 16 B = 1 KB contiguous per instr.
    const float* aBase = A + (size_t)(mt * BM + 8 * w) * VDIM + kb + 4 * l;

    // fragment identity: wave w owns col-fragments {2w, 2w+1}
    const int rl = l & 15, kg = l >> 4;
    const int cf0 = 2 * w;

    char* const lb = (char*)&lds[0];
    const int fro = rl * (PITCH * 2) + kg * 16;     // fragment read offset (+j*64)
    const int swo = (8 * w) * (PITCH * 2) + l * 8;  // stage write offset (+i rows)

    float4_t acc[2][2];
    #pragma unroll
    for (int i = 0; i < 2; ++i)
        #pragma unroll
        for (int j = 0; j < 2; ++j) acc[i][j] = (float4_t){0.f, 0.f, 0.f, 0.f};

    float4_t fs[8];                             // depth-1 prefetch: 32 VGPR

    auto nk_of = [&](int ssn) {
        int r = nsteps - ssn * BKS;
        return r < 0 ? 0 : (r > BKS ? BKS : r);
    };
    auto loadA = [&](int ssn, int nk) {         // 8 x 1KB contiguous instrs
        const float* p = aBase + (size_t)ssn * (BKS * 32);
        const bool act = l < 8 * nk;            // ragged-tail guard, no OOB
        #pragma unroll
        for (int i = 0; i < 8; ++i)
            if (act) __builtin_memcpy(&fs[i], p + (size_t)i * VDIM, 16);
    };
    auto writeA = [&](int nk) {                 // ds_write_b64, 2-way banks (free)
        const bool act = l < 8 * nk;
        #pragma unroll
        for (int i = 0; i < 8; ++i)
            if (act) {
                uint2 v;
                v.x = pack_bf2(fs[i][0], fs[i][1]);
                v.y = pack_bf2(fs[i][2], fs[i][3]);
                *reinterpret_cast<uint2*>(lb + swo + i * (PITCH * 2)) = v;
            }
    };
    auto computeSS = [&](int ss, int curn) {
        const int g0 = start + ss * BKS;
        #pragma unroll
        for (int j = 0; j < BKS; ++j)
            if (j < curn) {
                const short* bb = Wt2 + (size_t)(g0 + j) * 4096
                                + (size_t)(cf0 * 16 + rl) * 32 + kg * 8;
                short8_t b0 = *reinterpret_cast<const short8_t*>(bb);
                short8_t b1 = *reinterpret_cast<const short8_t*>(bb + 512);
                short8_t a0 = *reinterpret_cast<const short8_t*>(lb + fro + j * 64);
                short8_t a1 = *reinterpret_cast<const short8_t*>(lb + fro + 16 * (PITCH * 2) + j * 64);
                acc[0][0] = __builtin_amdgcn_mfma_f32_16x16x32_bf16(a0, b0, acc[0][0], 0, 0, 0);
                acc[0][1] = __builtin_amdgcn_mfma_f32_16x16x32_bf16(a0, b1, acc[0][1], 0, 0, 0);
                acc[1][0] = __builtin_amdgcn_mfma_f32_16x16x32_bf16(a1, b0, acc[1][0], 0, 0, 0);
                acc[1][1] = __builtin_amdgcn_mfma_f32_16x16x32_bf16(a1, b1, acc[1][1], 0, 0, 0);
            }
    };

    // prologue: stage superstep 0
    loadA(0, nk_of(0));
    writeA(nk_of(0));
    asm volatile("s_waitcnt lgkmcnt(0)" ::: "memory");
    __builtin_amdgcn_sched_barrier(0);
    __builtin_amdgcn_s_barrier();

    #pragma unroll 1
    for (int ss = 0; ss < NSS; ++ss) {
        const int n1 = nk_of(ss + 1);
        if (n1 > 0) loadA(ss + 1, n1);          // issue next batch; completes
        __builtin_amdgcn_sched_barrier(0);      // under this superstep's MFMA
        computeSS(ss, nk_of(ss));
        // barrier 1: all waves done READING the buffer before overwrite
        asm volatile("" ::: "memory");
        __builtin_amdgcn_sched_barrier(0);
        __builtin_amdgcn_s_barrier();
        if (n1 > 0) {
            writeA(n1);                         // waits only its own loads (reg dep)
            asm volatile("s_waitcnt lgkmcnt(0)" ::: "memory");
            __builtin_amdgcn_sched_barrier(0);
            __builtin_amdgcn_s_barrier();       // barrier 2: writes visible
        }
    }

    // Partial write: C/D layout col = lane&15, row = (lane>>4)*4 + j  [m89-verified]
    float* pout = P + ((size_t)s * MROWS + (size_t)mt * BM) * EDIM + cf0 * 16;
    #pragma unroll
    for (int rf = 0; rf < 2; ++rf)
        #pragma unroll
        for (int cf = 0; cf < 2; ++cf)
            #pragma unroll
            for (int j = 0; j < 4; ++j) {
                int rr = rf * 16 + kg * 4 + j;
                int cc = cf * 16 + rl;
                pout[(size_t)rr * EDIM + cc] = acc[rf][cf][j];
            }
}

// out = bias + sum of SPLIT partials + fp32 K-tail, float4-vectorized.
__global__ __launch_bounds__(256) void k_reduce(const float* __restrict__ P,
                                                const float* __restrict__ A,
                                                const float* __restrict__ W,
                                                const float* __restrict__ bias,
                                                float* __restrict__ out) {
    const int i4 = blockIdx.x * 256 + threadIdx.x;   // float4 index, 65536 total
    const int m  = i4 >> 5;                          // 32 float4 per output row
    const int e4 = i4 & 31;
    float4_t acc = reinterpret_cast<const float4_t*>(bias)[e4];
    #pragma unroll
    for (int j = 0; j < KTAIL; ++j) {
        float a = A[(size_t)m * VDIM + KMAIN + j];
        float4_t w = reinterpret_cast<const float4_t*>(W + (size_t)(KMAIN + j) * EDIM)[e4];
        acc += a * w;
    }
    float4_t ps = {0.f, 0.f, 0.f, 0.f};
    #pragma unroll
    for (int p = 0; p < SPLIT; ++p)
        ps += reinterpret_cast<const float4_t*>(P)[(size_t)p * (MROWS * EDIM / 4) + i4];
    acc += ps;
    reinterpret_cast<float4_t*>(out)[i4] = acc;
}

// Emergency fallback if workspace is too small: plain fp32, deterministic.
__global__ __launch_bounds__(256) void k_naive(const float* __restrict__ A,
                                               const float* __restrict__ W,
                                               const float* __restrict__ bias,
                                               float* __restrict__ out) {
    const int e  = threadIdx.x & 127;
    const int mi = threadIdx.x >> 7;
    const int m0 = blockIdx.x * 8 + mi;
    float acc[4] = {0.f, 0.f, 0.f, 0.f};
    for (int k = 0; k < VDIM; ++k) {
        float w = W[(size_t)k * EDIM + e];
        #pragma unroll
        for (int q = 0; q < 4; ++q)
            acc[q] += A[(size_t)(m0 + q * 2) * VDIM + k] * w;
    }
    #pragma unroll
    for (int q = 0; q < 4; ++q)
        out[(size_t)(m0 + q * 2) * EDIM + e] = acc[q] + bias[e];
}

extern "C" void kernel_launch(void* const* d_in, const int* in_sizes, int n_in,
                              void* d_out, int out_size, void* d_ws, size_t ws_size,
                              hipStream_t stream) {
    const float* A    = (const float*)d_in[0];  // (16,128,50257) fp32
    const float* W    = (const float*)d_in[1];  // (50257,128) fp32
    const float* bias = (const float*)d_in[2];  // (128,) fp32
    float* out = (float*)d_out;                 // (16,128,128) fp32

    const size_t WT2_BYTES = (size_t)KSTEPS * 4096 * sizeof(short);         // 12.86 MB
    const size_t P_BYTES   = (size_t)SPLIT * MROWS * EDIM * sizeof(float);  // 25.17 MB

    if (ws_size >= WT2_BYTES + P_BYTES) {
        short* Wt2 = (short*)d_ws;
        float* P   = (float*)((char*)d_ws + WT2_BYTES);
        k_wt2<<<KSTEPS, 256, 0, stream>>>(W, Wt2);
        k_main<<<(MROWS / BM) * SPLIT, 256, 0, stream>>>(A, Wt2, P);
        k_reduce<<<(MROWS * EDIM) / (256 * 4), 256, 0, stream>>>(P, A, W, bias, out);
    } else {
        k_naive<<<MROWS / 8, 256, 0, stream>>>(A, W, bias, out);
    }
}